// Round 1
// baseline (402.243 us; speedup 1.0000x reference)
//
#include <hip/hip_runtime.h>
#include <math.h>

#define B_N 8192
#define K_N 256
#define D_N 768

static constexpr float ALPHA_C = 0.2f;
static constexpr float BETA_C  = 0.3f;
static constexpr float EPS_C   = 1e-8f;
static constexpr float NEG_INF_C = -10000.0f;
static constexpr float INV_WTEMP = 20.0f;   // 1/0.05

// ---------------------------------------------------------------------------
// K0: normalize centroid rows, write TRANSPOSED CnT[768][256] into ws
// ---------------------------------------------------------------------------
__global__ __launch_bounds__(256) void k_centroid_prep(
        const float* __restrict__ centroid, float* __restrict__ cnt) {
    int c = blockIdx.x, t = threadIdx.x;
    const float* p = centroid + c * D_N;
    float v0 = p[t], v1 = p[t + 256], v2 = p[t + 512];
    float s = v0 * v0 + v1 * v1 + v2 * v2;
    #pragma unroll
    for (int o = 32; o >= 1; o >>= 1) s += __shfl_xor(s, o);
    __shared__ float red[4];
    __shared__ float sinv;
    if ((t & 63) == 0) red[t >> 6] = s;
    __syncthreads();
    if (t == 0)
        sinv = 1.0f / fmaxf(sqrtf(red[0] + red[1] + red[2] + red[3]), EPS_C);
    __syncthreads();
    float inv = sinv;
    cnt[(t)       * K_N + c] = v0 * inv;
    cnt[(t + 256) * K_N + c] = v1 * inv;
    cnt[(t + 512) * K_N + c] = v2 * inv;
}

// ---------------------------------------------------------------------------
// K0b: 1/max(||dp_i||, eps) for every datapoint row
// ---------------------------------------------------------------------------
__global__ __launch_bounds__(256) void k_rnorm(
        const float* __restrict__ dp, float* __restrict__ rnorm) {
    int i = blockIdx.x, t = threadIdx.x;
    const float* p = dp + (size_t)i * D_N;
    float v0 = p[t], v1 = p[t + 256], v2 = p[t + 512];
    float s = v0 * v0 + v1 * v1 + v2 * v2;
    #pragma unroll
    for (int o = 32; o >= 1; o >>= 1) s += __shfl_xor(s, o);
    __shared__ float red[4];
    if ((t & 63) == 0) red[t >> 6] = s;
    __syncthreads();
    if (t == 0) {
        float n = sqrtf(red[0] + red[1] + red[2] + red[3]);
        rnorm[i] = 1.0f / fmaxf(n, EPS_C);
    }
}

// ---------------------------------------------------------------------------
// K1: intra_cos_sim = (dp @ CnT) * rnorm  -- fp32 tiled GEMM, M=8192 N=256 K=768
// one block = 16 rows x 256 centroids; thread t owns centroid column t
// ---------------------------------------------------------------------------
#define TM 16
#define KC 64
__global__ __launch_bounds__(256) void k_intra(
        const float* __restrict__ dp, const float* __restrict__ cnt,
        const float* __restrict__ rnorm, float* __restrict__ out) {
    int c = threadIdx.x;
    int row0 = blockIdx.x * TM;
    __shared__ float tile[TM][KC];
    float acc[TM];
    #pragma unroll
    for (int m = 0; m < TM; ++m) acc[m] = 0.f;

    for (int kb = 0; kb < D_N; kb += KC) {
        __syncthreads();
        #pragma unroll
        for (int u = 0; u < (TM * KC) / 256; ++u) {
            int idx = threadIdx.x + u * 256;
            int m = idx / KC, k = idx % KC;
            tile[m][k] = dp[(size_t)(row0 + m) * D_N + kb + k];
        }
        __syncthreads();
        #pragma unroll
        for (int kk = 0; kk < KC; kk += 4) {
            float cv0 = cnt[(kb + kk + 0) * K_N + c];
            float cv1 = cnt[(kb + kk + 1) * K_N + c];
            float cv2 = cnt[(kb + kk + 2) * K_N + c];
            float cv3 = cnt[(kb + kk + 3) * K_N + c];
            #pragma unroll
            for (int m = 0; m < TM; ++m) {
                acc[m] += cv0 * tile[m][kk] + cv1 * tile[m][kk + 1]
                        + cv2 * tile[m][kk + 2] + cv3 * tile[m][kk + 3];
            }
        }
    }
    #pragma unroll
    for (int m = 0; m < TM; ++m)
        out[(size_t)(row0 + m) * K_N + c] = acc[m] * rnorm[row0 + m];
}

// ---------------------------------------------------------------------------
// K2: per-row top-2 (tie-break lower index), write cid + gather centroid rows
// one wave (64 threads) per row
// ---------------------------------------------------------------------------
__device__ __forceinline__ bool top_better(float v, int iv, float w, int iw) {
    return (v > w) || ((v == w) && (iv < iw));
}

__global__ __launch_bounds__(64) void k_top2(
        const float* __restrict__ intra, const float* __restrict__ centroid,
        unsigned char* __restrict__ cid,
        float* __restrict__ dp_centroid, float* __restrict__ hard_negative) {
    int i = blockIdx.x;
    int l = threadIdx.x;
    float m1 = -1e30f, m2 = -1e30f;
    int i1 = K_N, i2 = K_N;
    #pragma unroll
    for (int u = 0; u < 4; ++u) {
        int c = l + 64 * u;
        float v = intra[(size_t)i * K_N + c];
        if (v > m1) { m2 = m1; i2 = i1; m1 = v; i1 = c; }
        else if (v > m2) { m2 = v; i2 = c; }
    }
    #pragma unroll
    for (int o = 32; o >= 1; o >>= 1) {
        float om1 = __shfl_xor(m1, o);
        int   oi1 = __shfl_xor(i1, o);
        float om2 = __shfl_xor(m2, o);
        int   oi2 = __shfl_xor(i2, o);
        if (top_better(om1, oi1, m1, i1)) {
            if (top_better(m1, i1, om2, oi2)) { m2 = m1; i2 = i1; }
            else                              { m2 = om2; i2 = oi2; }
            m1 = om1; i1 = oi1;
        } else if (top_better(om1, oi1, m2, i2)) {
            m2 = om1; i2 = oi1;
        }
    }
    if (l == 0) cid[i] = (unsigned char)i1;

    const float4* s1 = (const float4*)(centroid + (size_t)i1 * D_N);
    const float4* s2 = (const float4*)(centroid + (size_t)i2 * D_N);
    float4* d1 = (float4*)(dp_centroid   + (size_t)i * D_N);
    float4* d2 = (float4*)(hard_negative + (size_t)i * D_N);
    #pragma unroll
    for (int u = 0; u < 3; ++u) {
        d1[l + 64 * u] = s1[l + 64 * u];
        d2[l + 64 * u] = s2[l + 64 * u];
    }
}

// ---------------------------------------------------------------------------
// K3: fused per-row pass over batch_cos_sim:
//     dp_cluster row, fn_loss partial, masked-softmax weights row
// one block (256 threads) per row; row staged once in LDS
// ---------------------------------------------------------------------------
__global__ __launch_bounds__(256) void k_row(
        const float* __restrict__ bcs, const unsigned char* __restrict__ cid_g,
        float* __restrict__ dp_cluster, float* __restrict__ weights,
        double* __restrict__ acc) {
    int i = blockIdx.x;
    int t = threadIdx.x;
    __shared__ float4 row4[B_N / 4];           // 32 KB
    __shared__ uint4  cid4[B_N / 16];          // 8 KB
    __shared__ float  red[4];
    float* row = (float*)row4;
    const unsigned char* cid = (const unsigned char*)cid4;

    // stage cluster ids
    #pragma unroll
    for (int u = 0; u < 2; ++u)
        cid4[t + 256 * u] = ((const uint4*)cid_g)[t + 256 * u];

    // stage row + masked max
    const float4* src = (const float4*)(bcs + (size_t)i * B_N);
    float mx = -3.0e38f;
    #pragma unroll
    for (int u = 0; u < 8; ++u) {
        int f4 = t + 256 * u;
        float4 v = src[f4];
        row4[f4] = v;
        int j0 = f4 * 4;
        float a = (j0     == i) ? NEG_INF_C : v.x;
        float b = (j0 + 1 == i) ? NEG_INF_C : v.y;
        float c = (j0 + 2 == i) ? NEG_INF_C : v.z;
        float d = (j0 + 3 == i) ? NEG_INF_C : v.w;
        mx = fmaxf(mx, fmaxf(fmaxf(a, b), fmaxf(c, d)));
    }
    __syncthreads();     // row + cid visible
    #pragma unroll
    for (int o = 32; o >= 1; o >>= 1) mx = fmaxf(mx, __shfl_xor(mx, o));
    if ((t & 63) == 0) red[t >> 6] = mx;
    __syncthreads();
    mx = fmaxf(fmaxf(red[0], red[1]), fmaxf(red[2], red[3]));

    float pos = row[i];
    unsigned char myc = cid[i];
    __syncthreads();     // everyone read pos / finished with red before row overwrite

    float fn = 0.f, se = 0.f;
    float* dcrow = dp_cluster + (size_t)i * B_N;
    #pragma unroll
    for (int r = 0; r < 8; ++r) {
        int f4 = t + 256 * r;
        int j0 = f4 * 4;
        float4 v = row4[f4];
        float4 e, dc;
        {
            bool same = (cid[j0] == myc) & (j0 != i);
            float delta = same ? (v.x - pos) : 0.f;
            fn += fmaxf(delta + ALPHA_C, 0.f) + fmaxf(-delta - BETA_C, 0.f);
            dc.x = same ? 1.0f : 0.f;
            e.x = __expf(((j0 == i) ? NEG_INF_C : v.x) - mx);
        }
        {
            bool same = (cid[j0 + 1] == myc) & (j0 + 1 != i);
            float delta = same ? (v.y - pos) : 0.f;
            fn += fmaxf(delta + ALPHA_C, 0.f) + fmaxf(-delta - BETA_C, 0.f);
            dc.y = same ? 1.0f : 0.f;
            e.y = __expf(((j0 + 1 == i) ? NEG_INF_C : v.y) - mx);
        }
        {
            bool same = (cid[j0 + 2] == myc) & (j0 + 2 != i);
            float delta = same ? (v.z - pos) : 0.f;
            fn += fmaxf(delta + ALPHA_C, 0.f) + fmaxf(-delta - BETA_C, 0.f);
            dc.z = same ? 1.0f : 0.f;
            e.z = __expf(((j0 + 2 == i) ? NEG_INF_C : v.z) - mx);
        }
        {
            bool same = (cid[j0 + 3] == myc) & (j0 + 3 != i);
            float delta = same ? (v.w - pos) : 0.f;
            fn += fmaxf(delta + ALPHA_C, 0.f) + fmaxf(-delta - BETA_C, 0.f);
            dc.w = same ? 1.0f : 0.f;
            e.w = __expf(((j0 + 3 == i) ? NEG_INF_C : v.w) - mx);
        }
        se += e.x + e.y + e.z + e.w;
        row4[f4] = e;                       // overwrite own slots with exp values
        ((float4*)dcrow)[f4] = dc;
    }

    // sum(exp) reduce
    #pragma unroll
    for (int o = 32; o >= 1; o >>= 1) se += __shfl_xor(se, o);
    if ((t & 63) == 0) red[t >> 6] = se;
    __syncthreads();
    se = red[0] + red[1] + red[2] + red[3];
    float inv = INV_WTEMP / se;

    // weights: base has odd float offset -> scalar coalesced stores
    float* wrow = weights + (size_t)i * B_N;
    #pragma unroll
    for (int r = 0; r < 32; ++r) {
        int j = t + 256 * r;
        wrow[j] = row[j] * inv;
    }

    // fn_loss partial
    #pragma unroll
    for (int o = 32; o >= 1; o >>= 1) fn += __shfl_xor(fn, o);
    __syncthreads();     // done reading red (se)
    if ((t & 63) == 0) red[t >> 6] = fn;
    __syncthreads();
    if (t == 0) atomicAdd(acc, (double)(red[0] + red[1] + red[2] + red[3]));
}

// ---------------------------------------------------------------------------
// K4: finalize fn_loss = acc / B^2
// ---------------------------------------------------------------------------
__global__ void k_final(const double* __restrict__ acc, float* __restrict__ out) {
    out[0] = (float)(acc[0] / ((double)B_N * (double)B_N));
}

// ---------------------------------------------------------------------------
extern "C" void kernel_launch(void* const* d_in, const int* in_sizes, int n_in,
                              void* d_out, int out_size, void* d_ws, size_t ws_size,
                              hipStream_t stream) {
    const float* dp       = (const float*)d_in[0];
    const float* centroid = (const float*)d_in[1];
    const float* bcs      = (const float*)d_in[2];
    float* out = (float*)d_out;

    float* intra       = out;                       // [8192,256]
    float* dp_cluster  = out + 2097152;             // [8192,8192]
    float* dp_centroid = out + 69206016;            // [8192,768]
    float* hard_neg    = out + 75497472;            // [8192,768]
    float* fn_out      = out + 81788928;            // [1]
    float* weights     = out + 81788929;            // [8192,8192]

    char* ws = (char*)d_ws;
    double*        acc   = (double*)ws;                               // 8 B
    float*         cnt   = (float*)(ws + 256);                        // 768*256*4
    float*         rnorm = (float*)(ws + 256 + 786432);               // 8192*4
    unsigned char* cid   = (unsigned char*)(ws + 256 + 786432 + 32768); // 8192

    hipMemsetAsync(acc, 0, sizeof(double), stream);
    k_centroid_prep<<<K_N, 256, 0, stream>>>(centroid, cnt);
    k_rnorm<<<B_N, 256, 0, stream>>>(dp, rnorm);
    k_intra<<<B_N / TM, 256, 0, stream>>>(dp, cnt, rnorm, intra);
    k_top2<<<B_N, 64, 0, stream>>>(intra, centroid, cid, dp_centroid, hard_neg);
    k_row<<<B_N, 256, 0, stream>>>(bcs, cid, dp_cluster, weights, acc);
    k_final<<<1, 1, 0, stream>>>(acc, fn_out);
}

// Round 2
// 244.112 us; speedup vs baseline: 1.6478x; 1.6478x over previous
//
#include <hip/hip_runtime.h>
#include <math.h>

#define B_N 8192
#define K_N 256
#define D_N 768

static constexpr float ALPHA_C = 0.2f;
static constexpr float BETA_C  = 0.3f;
static constexpr float EPS_C   = 1e-8f;
static constexpr float NEG_INF_C = -10000.0f;
static constexpr float INV_WTEMP = 20.0f;   // 1/0.05

// ---------------------------------------------------------------------------
// K0: normalize centroid rows, write TRANSPOSED CnT[768][256] into ws
// ---------------------------------------------------------------------------
__global__ __launch_bounds__(256) void k_centroid_prep(
        const float* __restrict__ centroid, float* __restrict__ cnt) {
    int c = blockIdx.x, t = threadIdx.x;
    const float* p = centroid + c * D_N;
    float v0 = p[t], v1 = p[t + 256], v2 = p[t + 512];
    float s = v0 * v0 + v1 * v1 + v2 * v2;
    #pragma unroll
    for (int o = 32; o >= 1; o >>= 1) s += __shfl_xor(s, o);
    __shared__ float red[4];
    __shared__ float sinv;
    if ((t & 63) == 0) red[t >> 6] = s;
    __syncthreads();
    if (t == 0)
        sinv = 1.0f / fmaxf(sqrtf(red[0] + red[1] + red[2] + red[3]), EPS_C);
    __syncthreads();
    float inv = sinv;
    cnt[(t)       * K_N + c] = v0 * inv;
    cnt[(t + 256) * K_N + c] = v1 * inv;
    cnt[(t + 512) * K_N + c] = v2 * inv;
}

// ---------------------------------------------------------------------------
// K0b: 1/max(||dp_i||, eps) for every datapoint row
// ---------------------------------------------------------------------------
__global__ __launch_bounds__(256) void k_rnorm(
        const float* __restrict__ dp, float* __restrict__ rnorm) {
    int i = blockIdx.x, t = threadIdx.x;
    const float* p = dp + (size_t)i * D_N;
    float v0 = p[t], v1 = p[t + 256], v2 = p[t + 512];
    float s = v0 * v0 + v1 * v1 + v2 * v2;
    #pragma unroll
    for (int o = 32; o >= 1; o >>= 1) s += __shfl_xor(s, o);
    __shared__ float red[4];
    if ((t & 63) == 0) red[t >> 6] = s;
    __syncthreads();
    if (t == 0) {
        float n = sqrtf(red[0] + red[1] + red[2] + red[3]);
        rnorm[i] = 1.0f / fmaxf(n, EPS_C);
    }
}

// ---------------------------------------------------------------------------
// K1: intra_cos_sim = (dp @ CnT) * rnorm  -- fp32 register-tiled GEMM
// block = 32 rows x 256 cols, 256 threads, micro-tile 8x4 per thread
// DS per k per thread: 2 b128 (dp, wave-uniform broadcast) + 1 b128 (cnt)
// for 32 FMAs -> DS wall ~47us, VALU wall ~21us
// ---------------------------------------------------------------------------
#define BM 32
#define KC 32
__global__ __launch_bounds__(256) void k_intra(
        const float* __restrict__ dp, const float* __restrict__ cnt,
        const float* __restrict__ rnorm, float* __restrict__ out) {
    __shared__ float ct[KC][K_N];        // 32 KB
    __shared__ float dpt[KC][BM + 4];    // 4.6 KB, row stride 36*4=144 B (16B-aligned)
    int t = threadIdx.x;
    int row0 = blockIdx.x * BM;
    int tx = t & 63, ty = t >> 6;
    int c0 = tx * 4;                      // centroid col base
    int r0 = ty * 8;                      // row base (wave-uniform)

    float acc[8][4];
    #pragma unroll
    for (int r = 0; r < 8; ++r)
        #pragma unroll
        for (int c = 0; c < 4; ++c) acc[r][c] = 0.f;

    // dp staging source: thread -> one float4 (32 rows x 8 k-quads)
    int sr = t >> 3, skq = t & 7;

    for (int kb = 0; kb < D_N; kb += KC) {
        __syncthreads();
        // stage cnt tile [KC][256]
        #pragma unroll
        for (int u = 0; u < 8; ++u) {
            int f4 = t + 256 * u;                 // 0..2047
            int k = f4 >> 6, c4 = (f4 & 63) << 2;
            *(float4*)&ct[k][c4] = *(const float4*)&cnt[(size_t)(kb + k) * K_N + c4];
        }
        // stage dp tile transposed dpt[k][r]
        {
            float4 v = *(const float4*)&dp[(size_t)(row0 + sr) * D_N + kb + skq * 4];
            dpt[skq * 4 + 0][sr] = v.x;
            dpt[skq * 4 + 1][sr] = v.y;
            dpt[skq * 4 + 2][sr] = v.z;
            dpt[skq * 4 + 3][sr] = v.w;
        }
        __syncthreads();
        #pragma unroll
        for (int k = 0; k < KC; ++k) {
            float4 b4 = *(float4*)&ct[k][c0];
            float4 a0 = *(float4*)&dpt[k][r0];
            float4 a1 = *(float4*)&dpt[k][r0 + 4];
            float a[8] = {a0.x, a0.y, a0.z, a0.w, a1.x, a1.y, a1.z, a1.w};
            float b[4] = {b4.x, b4.y, b4.z, b4.w};
            #pragma unroll
            for (int r = 0; r < 8; ++r)
                #pragma unroll
                for (int c = 0; c < 4; ++c)
                    acc[r][c] += a[r] * b[c];
        }
    }

    #pragma unroll
    for (int r = 0; r < 8; ++r) {
        float rn = rnorm[row0 + r0 + r];
        float4 o;
        o.x = acc[r][0] * rn; o.y = acc[r][1] * rn;
        o.z = acc[r][2] * rn; o.w = acc[r][3] * rn;
        *(float4*)&out[(size_t)(row0 + r0 + r) * K_N + c0] = o;
    }
}

// ---------------------------------------------------------------------------
// K2: per-row top-2 (tie-break lower index), write cid + gather centroid rows
// one wave (64 threads) per row
// ---------------------------------------------------------------------------
__device__ __forceinline__ bool top_better(float v, int iv, float w, int iw) {
    return (v > w) || ((v == w) && (iv < iw));
}

__global__ __launch_bounds__(64) void k_top2(
        const float* __restrict__ intra, const float* __restrict__ centroid,
        unsigned char* __restrict__ cid,
        float* __restrict__ dp_centroid, float* __restrict__ hard_negative) {
    int i = blockIdx.x;
    int l = threadIdx.x;
    float m1 = -1e30f, m2 = -1e30f;
    int i1 = K_N, i2 = K_N;
    #pragma unroll
    for (int u = 0; u < 4; ++u) {
        int c = l + 64 * u;
        float v = intra[(size_t)i * K_N + c];
        if (v > m1) { m2 = m1; i2 = i1; m1 = v; i1 = c; }
        else if (v > m2) { m2 = v; i2 = c; }
    }
    #pragma unroll
    for (int o = 32; o >= 1; o >>= 1) {
        float om1 = __shfl_xor(m1, o);
        int   oi1 = __shfl_xor(i1, o);
        float om2 = __shfl_xor(m2, o);
        int   oi2 = __shfl_xor(i2, o);
        if (top_better(om1, oi1, m1, i1)) {
            if (top_better(m1, i1, om2, oi2)) { m2 = m1; i2 = i1; }
            else                              { m2 = om2; i2 = oi2; }
            m1 = om1; i1 = oi1;
        } else if (top_better(om1, oi1, m2, i2)) {
            m2 = om1; i2 = oi1;
        }
    }
    if (l == 0) cid[i] = (unsigned char)i1;

    const float4* s1 = (const float4*)(centroid + (size_t)i1 * D_N);
    const float4* s2 = (const float4*)(centroid + (size_t)i2 * D_N);
    float4* d1 = (float4*)(dp_centroid   + (size_t)i * D_N);
    float4* d2 = (float4*)(hard_negative + (size_t)i * D_N);
    #pragma unroll
    for (int u = 0; u < 3; ++u) {
        d1[l + 64 * u] = s1[l + 64 * u];
        d2[l + 64 * u] = s2[l + 64 * u];
    }
}

// ---------------------------------------------------------------------------
// K3: fused per-row pass over batch_cos_sim:
//     dp_cluster row, fn_loss partial, masked-softmax weights row
// one block (256 threads) per row; row staged once in LDS
// ---------------------------------------------------------------------------
__global__ __launch_bounds__(256) void k_row(
        const float* __restrict__ bcs, const unsigned char* __restrict__ cid_g,
        float* __restrict__ dp_cluster, float* __restrict__ weights,
        double* __restrict__ acc) {
    int i = blockIdx.x;
    int t = threadIdx.x;
    __shared__ float4 row4[B_N / 4];           // 32 KB
    __shared__ uint4  cid4[B_N / 16];          // 8 KB
    __shared__ float  red[4];
    float* row = (float*)row4;
    const unsigned char* cid = (const unsigned char*)cid4;

    // stage cluster ids
    #pragma unroll
    for (int u = 0; u < 2; ++u)
        cid4[t + 256 * u] = ((const uint4*)cid_g)[t + 256 * u];

    // stage row + masked max
    const float4* src = (const float4*)(bcs + (size_t)i * B_N);
    float mx = -3.0e38f;
    #pragma unroll
    for (int u = 0; u < 8; ++u) {
        int f4 = t + 256 * u;
        float4 v = src[f4];
        row4[f4] = v;
        int j0 = f4 * 4;
        float a = (j0     == i) ? NEG_INF_C : v.x;
        float b = (j0 + 1 == i) ? NEG_INF_C : v.y;
        float c = (j0 + 2 == i) ? NEG_INF_C : v.z;
        float d = (j0 + 3 == i) ? NEG_INF_C : v.w;
        mx = fmaxf(mx, fmaxf(fmaxf(a, b), fmaxf(c, d)));
    }
    __syncthreads();     // row + cid visible
    #pragma unroll
    for (int o = 32; o >= 1; o >>= 1) mx = fmaxf(mx, __shfl_xor(mx, o));
    if ((t & 63) == 0) red[t >> 6] = mx;
    __syncthreads();
    mx = fmaxf(fmaxf(red[0], red[1]), fmaxf(red[2], red[3]));

    float pos = row[i];
    unsigned char myc = cid[i];
    __syncthreads();     // everyone read pos / finished with red before row overwrite

    float fn = 0.f, se = 0.f;
    float* dcrow = dp_cluster + (size_t)i * B_N;
    #pragma unroll
    for (int r = 0; r < 8; ++r) {
        int f4 = t + 256 * r;
        int j0 = f4 * 4;
        float4 v = row4[f4];
        float4 e, dc;
        {
            bool same = (cid[j0] == myc) & (j0 != i);
            float delta = same ? (v.x - pos) : 0.f;
            fn += fmaxf(delta + ALPHA_C, 0.f) + fmaxf(-delta - BETA_C, 0.f);
            dc.x = same ? 1.0f : 0.f;
            e.x = __expf(((j0 == i) ? NEG_INF_C : v.x) - mx);
        }
        {
            bool same = (cid[j0 + 1] == myc) & (j0 + 1 != i);
            float delta = same ? (v.y - pos) : 0.f;
            fn += fmaxf(delta + ALPHA_C, 0.f) + fmaxf(-delta - BETA_C, 0.f);
            dc.y = same ? 1.0f : 0.f;
            e.y = __expf(((j0 + 1 == i) ? NEG_INF_C : v.y) - mx);
        }
        {
            bool same = (cid[j0 + 2] == myc) & (j0 + 2 != i);
            float delta = same ? (v.z - pos) : 0.f;
            fn += fmaxf(delta + ALPHA_C, 0.f) + fmaxf(-delta - BETA_C, 0.f);
            dc.z = same ? 1.0f : 0.f;
            e.z = __expf(((j0 + 2 == i) ? NEG_INF_C : v.z) - mx);
        }
        {
            bool same = (cid[j0 + 3] == myc) & (j0 + 3 != i);
            float delta = same ? (v.w - pos) : 0.f;
            fn += fmaxf(delta + ALPHA_C, 0.f) + fmaxf(-delta - BETA_C, 0.f);
            dc.w = same ? 1.0f : 0.f;
            e.w = __expf(((j0 + 3 == i) ? NEG_INF_C : v.w) - mx);
        }
        se += e.x + e.y + e.z + e.w;
        row4[f4] = e;                       // overwrite own slots with exp values
        ((float4*)dcrow)[f4] = dc;
    }

    // sum(exp) reduce
    #pragma unroll
    for (int o = 32; o >= 1; o >>= 1) se += __shfl_xor(se, o);
    if ((t & 63) == 0) red[t >> 6] = se;
    __syncthreads();
    se = red[0] + red[1] + red[2] + red[3];
    float inv = INV_WTEMP / se;

    // weights: base has odd float offset -> scalar coalesced stores
    float* wrow = weights + (size_t)i * B_N;
    #pragma unroll
    for (int r = 0; r < 32; ++r) {
        int j = t + 256 * r;
        wrow[j] = row[j] * inv;
    }

    // fn_loss partial
    #pragma unroll
    for (int o = 32; o >= 1; o >>= 1) fn += __shfl_xor(fn, o);
    __syncthreads();     // done reading red (se)
    if ((t & 63) == 0) red[t >> 6] = fn;
    __syncthreads();
    if (t == 0) atomicAdd(acc, (double)(red[0] + red[1] + red[2] + red[3]));
}

// ---------------------------------------------------------------------------
// K4: finalize fn_loss = acc / B^2
// ---------------------------------------------------------------------------
__global__ void k_final(const double* __restrict__ acc, float* __restrict__ out) {
    out[0] = (float)(acc[0] / ((double)B_N * (double)B_N));
}

// ---------------------------------------------------------------------------
extern "C" void kernel_launch(void* const* d_in, const int* in_sizes, int n_in,
                              void* d_out, int out_size, void* d_ws, size_t ws_size,
                              hipStream_t stream) {
    const float* dp       = (const float*)d_in[0];
    const float* centroid = (const float*)d_in[1];
    const float* bcs      = (const float*)d_in[2];
    float* out = (float*)d_out;

    float* intra       = out;                       // [8192,256]
    float* dp_cluster  = out + 2097152;             // [8192,8192]
    float* dp_centroid = out + 69206016;            // [8192,768]
    float* hard_neg    = out + 75497472;            // [8192,768]
    float* fn_out      = out + 81788928;            // [1]
    float* weights     = out + 81788929;            // [8192,8192]

    char* ws = (char*)d_ws;
    double*        acc   = (double*)ws;                               // 8 B
    float*         cnt   = (float*)(ws + 256);                        // 768*256*4
    float*         rnorm = (float*)(ws + 256 + 786432);               // 8192*4
    unsigned char* cid   = (unsigned char*)(ws + 256 + 786432 + 32768); // 8192

    hipMemsetAsync(acc, 0, sizeof(double), stream);
    k_centroid_prep<<<K_N, 256, 0, stream>>>(centroid, cnt);
    k_rnorm<<<B_N, 256, 0, stream>>>(dp, rnorm);
    k_intra<<<B_N / BM, 256, 0, stream>>>(dp, cnt, rnorm, intra);
    k_top2<<<B_N, 64, 0, stream>>>(intra, centroid, cid, dp_centroid, hard_neg);
    k_row<<<B_N, 256, 0, stream>>>(bcs, cid, dp_cluster, weights, acc);
    k_final<<<1, 1, 0, stream>>>(acc, fn_out);
}